// Round 9
// baseline (84976.447 us; speedup 1.0000x reference)
//
#include <hip/hip_runtime.h>
#include <cmath>

#define VOCAB   4096
#define ENC_DIM 1024
#define PRED_H  640
#define JOINT_H 640
#define TMAX    128
#define MAX_SYM 30
#define NSTEPS  (TMAX*(MAX_SYM+1))   // 3968
#define NWG     256
#define NTHR    512
#define RLX __ATOMIC_RELAXED
#define AGT __HIP_MEMORY_SCOPE_AGENT

typedef unsigned long long u64;
typedef __attribute__((ext_vector_type(4))) float f32x4;
typedef __attribute__((ext_vector_type(4))) unsigned int u32x4;

// ws layout (bytes) — single copy, IC-resident (~10.3 KB):
//   0    : cntA u32 ; 64: cntB ; 128: cntH ; 192: cntP   (monotonic counters)
//   256  : parts[256] u64  (argmax entries: key<<32 | (4095-r))
//   2560 : h0n[640] f32
//   5120 : h1n[640] f32
//   7680 : hid[640] f32      -> ends 10240

__device__ __forceinline__ float wave_red(float v){
  v += __shfl_xor(v, 32, 64);
  v += __shfl_xor(v, 16, 64);
  v += __shfl_xor(v,  8, 64);
  v += __shfl_xor(v,  4, 64);
  v += __shfl_xor(v,  2, 64);
  v += __shfl_xor(v,  1, 64);
  return v;
}

__device__ __forceinline__ float sigf(float x){ return 1.0f/(1.0f+expf(-x)); }

__device__ __forceinline__ void cstore_f(float* p, float v){
  __hip_atomic_store((unsigned*)p, __float_as_uint(v), RLX, AGT);
}
__device__ __forceinline__ void cstore_u64(u64* p, u64 v){
  __hip_atomic_store(p, v, RLX, AGT);
}

// one-shot coherent 16B loads (bypass L1/L2 -> IC); NO implicit waitcnt
__device__ __forceinline__ f32x4 cload_f4(const float* p){
  f32x4 r;
  asm volatile("global_load_dwordx4 %0, %1, off sc0 sc1" : "=v"(r) : "v"(p));
  return r;
}
__device__ __forceinline__ u32x4 cload_u4(const u64* p){
  u32x4 r;
  asm volatile("global_load_dwordx4 %0, %1, off sc0 sc1" : "=v"(r) : "v"(p));
  return r;
}

// argmax entry: key(order-preserving f32 map) << 32 | (4095-r); max => argmax, ties->smallest r
__device__ __forceinline__ u64 mkentry(float lg, int r){
  unsigned u = __float_as_uint(lg);
  u = (u & 0x80000000u) ? ~u : (u | 0x80000000u);
  return ((u64)u<<32) | (u64)(4095 - r);
}

__global__ void init_ws(unsigned* ws){
  for (int i = threadIdx.x; i < 8192; i += 256) ws[i] = 0u;   // 32 KB
}

__global__ __launch_bounds__(NTHR, 2)
void rnnt_decode(const float* __restrict__ enc,
                 const int*   __restrict__ outlen_p,
                 const float* __restrict__ emb,
                 const float* __restrict__ Wih0, const float* __restrict__ Whh0, const float* __restrict__ b0,
                 const float* __restrict__ Wih1, const float* __restrict__ Whh1, const float* __restrict__ b1,
                 const float* __restrict__ Wj1,  const float* __restrict__ bj1,
                 const float* __restrict__ Wj2,  const float* __restrict__ bj2,
                 float* __restrict__ out,
                 unsigned* __restrict__ cnts,    // [4] at 16-word stride
                 u64* __restrict__ parts,        // [256]
                 float* __restrict__ h0n,        // [640]
                 float* __restrict__ h1n,        // [640]
                 float* __restrict__ hidg)       // [640]
{
  const int wg = blockIdx.x, tid = threadIdx.x;
  const int wave = tid >> 6, lane = tid & 63;
  const int timesteps = outlen_p[0];
  unsigned* cntA = cnts;      unsigned* cntB = cnts + 16;
  unsigned* cntH = cnts + 32; unsigned* cntP = cnts + 48;

  __shared__ float xa[PRED_H];
  __shared__ float xsh[ENC_DIM];
  __shared__ float h0buf[2][PRED_H];
  __shared__ float h1buf[2][PRED_H];
  __shared__ float hidsh[JOINT_H];
  __shared__ float zsh[4][4];
  __shared__ float zjs[8];
  __shared__ float zjs2[4];
  __shared__ float c0c[4], c1c[4], c0p[4], c1p[4];
  __shared__ u64 psh[8];
  __shared__ u64 pm[128];
  __shared__ int kshm;

  const int jb = (wg*PRED_H)/NWG;
  const int je = ((wg+1)*PRED_H)/NWG;
  const int nj = je - jb;                 // 2 or 3

  // ---- persistent LSTM weight registers (identical mapping to R5) ----
  const int riA = wave, riB = wave + 8;
  const int gA = riA & 3, jA = riA >> 2;
  const int gB = riB & 3, jBx = riB >> 2;
  const bool hasB = (riB < 4*nj);
  const int rowA = gA*PRED_H + jb + jA;
  const int rowB = hasB ? (gB*PRED_H + jb + jBx) : 0;

  float w0xA[10], w0hA[10], w0xB[10], w0hB[10];
  float w1xA[10], w1hA[10], w1xB[10], w1hB[10];
  #pragma unroll
  for (int i = 0; i < 10; ++i){
    int c = lane + (i<<6);
    w0xA[i] = Wih0[(size_t)rowA*PRED_H + c];
    w0hA[i] = Whh0[(size_t)rowA*PRED_H + c];
    w1xA[i] = Wih1[(size_t)rowA*PRED_H + c];
    w1hA[i] = Whh1[(size_t)rowA*PRED_H + c];
    w0xB[i] = hasB ? Wih0[(size_t)rowB*PRED_H + c] : 0.f;
    w0hB[i] = hasB ? Whh0[(size_t)rowB*PRED_H + c] : 0.f;
    w1xB[i] = hasB ? Wih1[(size_t)rowB*PRED_H + c] : 0.f;
    w1hB[i] = hasB ? Whh1[(size_t)rowB*PRED_H + c] : 0.f;
  }
  const float bA0 = b0[rowA], bA1 = b1[rowA];
  const float bB0 = hasB ? b0[rowB] : 0.f, bB1 = hasB ? b1[rowB] : 0.f;

  // ---- Wj1 per-role (waves 0-3: rows jb, jb+2; waves 4-7: row jb+1) ----
  const int vt = (wave < 4) ? wave*64 + lane : (wave-4)*64 + lane;  // 0..255
  float wjf0[4], wjh0[3], wjf2[4], wjh2[3];
  {
    int r0 = (wave < 4) ? jb : jb + 1;
    #pragma unroll
    for (int i = 0; i < 4; ++i) wjf0[i] = Wj1[(size_t)r0*(ENC_DIM+PRED_H) + vt + (i<<8)];
    #pragma unroll
    for (int i = 0; i < 3; ++i){
      int c = vt + (i<<8);
      wjh0[i] = (c < PRED_H) ? Wj1[(size_t)r0*(ENC_DIM+PRED_H) + ENC_DIM + c] : 0.f;
    }
    #pragma unroll
    for (int i = 0; i < 4; ++i) wjf2[i] = 0.f;
    #pragma unroll
    for (int i = 0; i < 3; ++i) wjh2[i] = 0.f;
    if (wave < 4 && nj == 3){
      int r2 = jb + 2;
      #pragma unroll
      for (int i = 0; i < 4; ++i) wjf2[i] = Wj1[(size_t)r2*(ENC_DIM+PRED_H) + vt + (i<<8)];
      #pragma unroll
      for (int i = 0; i < 3; ++i){
        int c = vt + (i<<8);
        wjh2[i] = (c < PRED_H) ? Wj1[(size_t)r2*(ENC_DIM+PRED_H) + ENC_DIM + c] : 0.f;
      }
    }
  }
  float bjr[3];
  bjr[0] = bj1[jb]; bjr[1] = bj1[jb+1]; bjr[2] = (nj == 3) ? bj1[jb+2] : 0.f;
  float ca0 = 0.f, ca2 = 0.f;

  // ---- Wj2: 16 rows per WG, 2 per wave ----
  const int rA2 = wg*16 + wave*2, rB2 = rA2 + 1;
  float wj2A[10], wj2B[10];
  #pragma unroll
  for (int i = 0; i < 10; ++i){
    int c = lane + (i<<6);
    wj2A[i] = Wj2[(size_t)rA2*JOINT_H + c];
    wj2B[i] = Wj2[(size_t)rB2*JOINT_H + c];
  }
  const float bjA2 = bj2[rA2], bjB2 = bj2[rB2];

  for (int i = tid; i < PRED_H; i += NTHR){ h0buf[0][i] = 0.f; h1buf[0][i] = 0.f; }
  if (tid < 4){ c0c[tid] = 0.f; c1c[tid] = 0.f; }
  __syncthreads();

  int cur = 0, t = 0, sa = 0, last = -1, cnt = 0, tStaged = -1;
  unsigned eA = 0, eB = 0, eH = 0, eP = 0;
  bool done = false, reuse = false;

  for (int s = 0; s < NSTEPS; ++s){
    if (done){
      if (wg < 8) out[(size_t)s*VOCAB + wg*NTHR + tid] = 0.f;
      continue;
    }

    if (!reuse){
      ++eA; ++eB;
      // ===== A: LSTM layer 0 (inputs all LDS-local) =====
      for (int i = tid; i < PRED_H; i += NTHR)
        xa[i] = (last >= 0) ? emb[(size_t)last*PRED_H + i] : 0.f;
      __syncthreads();
      {
        float acc = 0.f;
        #pragma unroll
        for (int i = 0; i < 10; ++i) acc = fmaf(w0xA[i], xa[lane+(i<<6)], acc);
        #pragma unroll
        for (int i = 0; i < 10; ++i) acc = fmaf(w0hA[i], h0buf[cur][lane+(i<<6)], acc);
        acc = wave_red(acc);
        if (lane == 0) zsh[gA][jA] = acc + bA0;
        if (hasB){
          float a2 = 0.f;
          #pragma unroll
          for (int i = 0; i < 10; ++i) a2 = fmaf(w0xB[i], xa[lane+(i<<6)], a2);
          #pragma unroll
          for (int i = 0; i < 10; ++i) a2 = fmaf(w0hB[i], h0buf[cur][lane+(i<<6)], a2);
          a2 = wave_red(a2);
          if (lane == 0) zsh[gB][jBx] = a2 + bB0;
        }
      }
      __syncthreads();
      if (tid < nj){
        float ig = sigf(zsh[0][tid]), fg = sigf(zsh[1][tid]);
        float gg = tanhf(zsh[2][tid]), og = sigf(zsh[3][tid]);
        float c2 = fg*c0c[tid] + ig*gg;
        c0p[tid] = c2;
        cstore_f(&h0n[jb+tid], og*tanhf(c2));
      }
      asm volatile("s_waitcnt vmcnt(0)" ::: "memory");
      if (tid == 0) __hip_atomic_fetch_add(cntA, 1u, RLX, AGT);

      // ===== B: LSTM layer 1 =====
      if (tid == 0){
        while (__hip_atomic_load(cntA, RLX, AGT) < eA*NWG) __builtin_amdgcn_s_sleep(1);
      }
      __syncthreads();
      {
        f32x4 v;
        if (tid < 160) v = cload_f4(h0n + (tid<<2));
        asm volatile("s_waitcnt vmcnt(0)" ::: "memory");
        __builtin_amdgcn_sched_barrier(0);
        if (tid < 160) *(f32x4*)&h0buf[cur^1][tid<<2] = v;
      }
      __syncthreads();
      {
        float acc = 0.f;
        #pragma unroll
        for (int i = 0; i < 10; ++i) acc = fmaf(w1xA[i], h0buf[cur^1][lane+(i<<6)], acc);
        #pragma unroll
        for (int i = 0; i < 10; ++i) acc = fmaf(w1hA[i], h1buf[cur][lane+(i<<6)], acc);
        acc = wave_red(acc);
        if (lane == 0) zsh[gA][jA] = acc + bA1;
        if (hasB){
          float a2 = 0.f;
          #pragma unroll
          for (int i = 0; i < 10; ++i) a2 = fmaf(w1xB[i], h0buf[cur^1][lane+(i<<6)], a2);
          #pragma unroll
          for (int i = 0; i < 10; ++i) a2 = fmaf(w1hB[i], h1buf[cur][lane+(i<<6)], a2);
          a2 = wave_red(a2);
          if (lane == 0) zsh[gB][jBx] = a2 + bB1;
        }
      }
      __syncthreads();
      if (tid < nj){
        float ig = sigf(zsh[0][tid]), fg = sigf(zsh[1][tid]);
        float gg = tanhf(zsh[2][tid]), og = sigf(zsh[3][tid]);
        float c2 = fg*c1c[tid] + ig*gg;
        c1p[tid] = c2;
        cstore_f(&h1n[jb+tid], og*tanhf(c2));
      }
      asm volatile("s_waitcnt vmcnt(0)" ::: "memory");
      if (tid == 0) __hip_atomic_fetch_add(cntB, 1u, RLX, AGT);
    }

    // ===== C: joint hidden (single-pass, all nj rows) =====
    {
      ++eH;
      int tcap = (t < TMAX-1) ? t : (TMAX-1);
      bool fNew = (tcap != tStaged);
      if (fNew)
        for (int i = tid; i < ENC_DIM; i += NTHR) xsh[i] = enc[(size_t)tcap*ENC_DIM + i];
      if (!reuse){
        if (tid == 0){
          while (__hip_atomic_load(cntB, RLX, AGT) < eB*NWG) __builtin_amdgcn_s_sleep(1);
        }
        __syncthreads();
        f32x4 v;
        if (tid < 160) v = cload_f4(h1n + (tid<<2));
        asm volatile("s_waitcnt vmcnt(0)" ::: "memory");
        __builtin_amdgcn_sched_barrier(0);
        if (tid < 160) *(f32x4*)&h1buf[cur^1][tid<<2] = v;
      }
      __syncthreads();
      if (fNew){
        float a = 0.f;
        #pragma unroll
        for (int i = 0; i < 4; ++i) a = fmaf(wjf0[i], xsh[vt+(i<<8)], a);
        ca0 = a;
        if (wave < 4 && nj == 3){
          float a2 = 0.f;
          #pragma unroll
          for (int i = 0; i < 4; ++i) a2 = fmaf(wjf2[i], xsh[vt+(i<<8)], a2);
          ca2 = a2;
        }
        tStaged = tcap;
      }
      {
        float acc = ca0;
        #pragma unroll
        for (int i = 0; i < 3; ++i){
          int c = vt + (i<<8);
          acc = fmaf(wjh0[i], h1buf[cur^1][(c < PRED_H) ? c : 0], acc);
        }
        acc = wave_red(acc);
        if (lane == 0) zjs[wave] = acc;
      }
      if (wave < 4 && nj == 3){
        float acc = ca2;
        #pragma unroll
        for (int i = 0; i < 3; ++i){
          int c = vt + (i<<8);
          acc = fmaf(wjh2[i], h1buf[cur^1][(c < PRED_H) ? c : 0], acc);
        }
        acc = wave_red(acc);
        if (lane == 0) zjs2[wave] = acc;
      }
      __syncthreads();
      if (tid == 0){
        float v0 = zjs[0]+zjs[1]+zjs[2]+zjs[3] + bjr[0];
        cstore_f(&hidg[jb],   v0 > 0.f ? v0 : 0.f);
        float v1 = zjs[4]+zjs[5]+zjs[6]+zjs[7] + bjr[1];
        cstore_f(&hidg[jb+1], v1 > 0.f ? v1 : 0.f);
        if (nj == 3){
          float v2 = zjs2[0]+zjs2[1]+zjs2[2]+zjs2[3] + bjr[2];
          cstore_f(&hidg[jb+2], v2 > 0.f ? v2 : 0.f);
        }
        asm volatile("s_waitcnt vmcnt(0)" ::: "memory");
        __hip_atomic_fetch_add(cntH, 1u, RLX, AGT);
      }
    }

    // ===== D: logits + argmax =====
    int k;
    {
      ++eP;
      if (tid == 0){
        while (__hip_atomic_load(cntH, RLX, AGT) < eH*NWG) __builtin_amdgcn_s_sleep(1);
      }
      __syncthreads();
      {
        f32x4 v;
        if (tid < 160) v = cload_f4(hidg + (tid<<2));
        asm volatile("s_waitcnt vmcnt(0)" ::: "memory");
        __builtin_amdgcn_sched_barrier(0);
        if (tid < 160) *(f32x4*)&hidsh[tid<<2] = v;
      }
      __syncthreads();
      float accA = 0.f, accB = 0.f;
      #pragma unroll
      for (int i = 0; i < 10; ++i){
        float h = hidsh[lane+(i<<6)];
        accA = fmaf(wj2A[i], h, accA);
        accB = fmaf(wj2B[i], h, accB);
      }
      accA = wave_red(accA);
      accB = wave_red(accB);
      if (lane == 0){
        float lgA = accA + bjA2, lgB = accB + bjB2;
        out[(size_t)s*VOCAB + rA2] = lgA;
        out[(size_t)s*VOCAB + rB2] = lgB;
        u64 eAe = mkentry(lgA, rA2), eBe = mkentry(lgB, rB2);
        psh[wave] = eAe > eBe ? eAe : eBe;
      }
      __syncthreads();
      if (tid == 0){
        u64 m = psh[0];
        #pragma unroll
        for (int w = 1; w < 8; ++w) if (psh[w] > m) m = psh[w];
        cstore_u64(&parts[wg], m);
        asm volatile("s_waitcnt vmcnt(0)" ::: "memory");
        __hip_atomic_fetch_add(cntP, 1u, RLX, AGT);
        while (__hip_atomic_load(cntP, RLX, AGT) < eP*NWG) __builtin_amdgcn_s_sleep(1);
      }
      __syncthreads();
      {
        u32x4 pv;
        if (tid < 128) pv = cload_u4(&parts[tid<<1]);
        asm volatile("s_waitcnt vmcnt(0)" ::: "memory");
        __builtin_amdgcn_sched_barrier(0);
        if (tid < 128){
          u64 e0 = ((u64)pv.y<<32) | pv.x;
          u64 e1 = ((u64)pv.w<<32) | pv.z;
          pm[tid] = e0 > e1 ? e0 : e1;
        }
      }
      __syncthreads();
      if (wave == 0){
        u64 m = pm[lane] > pm[lane+64] ? pm[lane] : pm[lane+64];
        #pragma unroll
        for (int off = 32; off; off >>= 1){
          u64 o = __shfl_xor(m, off, 64);
          if (o > m) m = o;
        }
        if (lane == 0) kshm = 4095 - (int)(m & 0xFFFull);
      }
      __syncthreads();
      k = kshm;
    }

    // ===== E: decision (replicated in every WG) =====
    bool stop = (k == 0) || (sa >= MAX_SYM);
    if (!stop){
      if (wg == 0 && tid == 0) out[(size_t)NSTEPS*VOCAB + cnt] = (float)k;
      if (tid < nj){ c0c[tid] = c0p[tid]; c1c[tid] = c1p[tid]; }
      cnt++; sa++; last = k; cur ^= 1; reuse = false;
    } else {
      sa = 0; t++; reuse = true;
      if (t >= timesteps) done = true;
    }
    __syncthreads();
  }

  // labels tail (-1) and cnt
  size_t lab = (size_t)NSTEPS*VOCAB;
  int gidx = wg*NTHR + tid;
  for (int i = cnt + gidx; i < NSTEPS; i += NWG*NTHR) out[lab + i] = -1.f;
  if (wg == 0 && tid == 0) out[lab + NSTEPS] = (float)cnt;
}

extern "C" void kernel_launch(void* const* d_in, const int* in_sizes, int n_in,
                              void* d_out, int out_size, void* d_ws, size_t ws_size,
                              hipStream_t stream) {
  const float* enc  = (const float*)d_in[0];
  const int*   olen = (const int*)  d_in[1];
  const float* emb  = (const float*)d_in[2];
  const float* Wih0 = (const float*)d_in[3];
  const float* Whh0 = (const float*)d_in[4];
  const float* b0   = (const float*)d_in[5];
  const float* Wih1 = (const float*)d_in[6];
  const float* Whh1 = (const float*)d_in[7];
  const float* b1   = (const float*)d_in[8];
  const float* Wj1  = (const float*)d_in[9];
  const float* bj1  = (const float*)d_in[10];
  const float* Wj2  = (const float*)d_in[11];
  const float* bj2  = (const float*)d_in[12];
  float* out = (float*)d_out;

  unsigned* cnts = (unsigned*)d_ws;
  u64* parts = (u64*)((char*)d_ws + 256);
  float* h0n = (float*)((char*)d_ws + 2560);
  float* h1n = (float*)((char*)d_ws + 5120);
  float* hidg = (float*)((char*)d_ws + 7680);

  init_ws<<<1, 256, 0, stream>>>((unsigned*)d_ws);

  void* args[] = {&enc,&olen,&emb,&Wih0,&Whh0,&b0,&Wih1,&Whh1,&b1,
                  &Wj1,&bj1,&Wj2,&bj2,&out,&cnts,&parts,&h0n,&h1n,&hidg};
  hipLaunchCooperativeKernel((const void*)rnnt_decode, dim3(NWG), dim3(NTHR),
                             args, 0, stream);
}

// Round 10
// 50327.762 us; speedup vs baseline: 1.6885x; 1.6885x over previous
//
#include <hip/hip_runtime.h>
#include <cmath>

#define VOCAB   4096
#define ENC_DIM 1024
#define PRED_H  640
#define JOINT_H 640
#define TMAX    128
#define MAX_SYM 30
#define NSTEPS  (TMAX*(MAX_SYM+1))   // 3968
#define NWG     160
#define NTHR    512
#define RLX __ATOMIC_RELAXED
#define AGT __HIP_MEMORY_SCOPE_AGENT

typedef unsigned long long u64;
typedef __attribute__((ext_vector_type(4))) unsigned int u32x4;

// ws layout (bytes) — single copy, IC-resident:
//   0     : parts[160] u64 (tagged argmax entries)        [0,1280)
//   4096  : bufsT[1280] u64: h0n(640) | h1n(640) tagged   [4096,14336)
//   14336 : hidT[640] u64 tagged                          [14336,19456)
// tagged word = (tag u32 << 32) | f32 bits. tag = s+1 (>=1; 0 = unwritten)

__device__ __forceinline__ float wave_red(float v){
  v += __shfl_xor(v, 32, 64);
  v += __shfl_xor(v, 16, 64);
  v += __shfl_xor(v,  8, 64);
  v += __shfl_xor(v,  4, 64);
  v += __shfl_xor(v,  2, 64);
  v += __shfl_xor(v,  1, 64);
  return v;
}

__device__ __forceinline__ float sigf(float x){ return 1.0f/(1.0f+expf(-x)); }

__device__ __forceinline__ void tstore(u64* p, float v, unsigned tag){
  __hip_atomic_store(p, ((u64)tag<<32) | (u64)__float_as_uint(v), RLX, AGT);
}

// one-shot coherent 16B load (no waitcnt inside; caller waits)
__device__ __forceinline__ u32x4 cload_u4(const u64* p){
  u32x4 r;
  asm volatile("global_load_dwordx4 %0, %1, off sc0 sc1" : "=v"(r) : "v"(p));
  return r;
}

// poll one 16B chunk (2 tagged u64) until both tags match; store to LDS pair.
__device__ __forceinline__ void pollchunk(u64* src, float* dst, unsigned tag, int c){
  u64* p = src + (c<<1);
  u32x4 v;
  for(;;){
    v = cload_u4(p);
    asm volatile("s_waitcnt vmcnt(0)" ::: "memory");
    if (v.y == tag && v.w == tag) break;
    __builtin_amdgcn_s_sleep(8);
  }
  __builtin_amdgcn_sched_barrier(0);
  dst[(c<<1)]   = __uint_as_float(v.x);
  dst[(c<<1)+1] = __uint_as_float(v.z);
}

// argmax entry: key(32b order-preserving) << 24 | (tag&0xFFF)<<12 | (4095-r)
__device__ __forceinline__ u64 mkentry(float lg, int r, unsigned ep){
  unsigned u = __float_as_uint(lg);
  u = (u & 0x80000000u) ? ~u : (u | 0x80000000u);
  return ((u64)u<<24) | ((u64)(ep&0xFFFu)<<12) | (u64)(4095 - r);
}

__global__ void init_ws(unsigned* ws){
  for (int i = threadIdx.x; i < 8192; i += 256) ws[i] = 0u;   // 32 KB
}

__global__ __launch_bounds__(NTHR, 2)
void rnnt_decode(const float* __restrict__ enc,
                 const int*   __restrict__ outlen_p,
                 const float* __restrict__ emb,
                 const float* __restrict__ Wih0, const float* __restrict__ Whh0, const float* __restrict__ b0,
                 const float* __restrict__ Wih1, const float* __restrict__ Whh1, const float* __restrict__ b1,
                 const float* __restrict__ Wj1,  const float* __restrict__ bj1,
                 const float* __restrict__ Wj2,  const float* __restrict__ bj2,
                 float* __restrict__ out,
                 u64* __restrict__ parts,        // [160]
                 u64* __restrict__ bufsT,        // [2*PRED_H]
                 u64* __restrict__ hidT)         // [JOINT_H]
{
  const int wg = blockIdx.x, tid = threadIdx.x;
  const int wave = tid >> 6, lane = tid & 63;
  const int timesteps = outlen_p[0];

  __shared__ float xa[PRED_H];
  __shared__ float xsh[ENC_DIM];
  __shared__ float h0buf[2][PRED_H];
  __shared__ float h1buf[2][PRED_H];
  __shared__ float hidsh[JOINT_H];
  __shared__ float zsh[4][4];
  __shared__ float zjsA[8], zjsB[8];
  __shared__ float c0c[4], c1c[4], c0p[4], c1p[4];
  __shared__ float bj1sh[4];
  __shared__ u64 psh[8];
  __shared__ u64 pmx[3];
  __shared__ int kshm;

  const int jb = wg*4;                    // uniform: 4 j per WG (640/160)

  // ---- LSTM rows: 16 per WG, wave -> gate g=wave&3, j's jb+(wave>>2), jb+(wave>>2)+2
  const int gA = wave & 3;
  const int jA = wave >> 2;               // 0..1
  const int rowA = gA*PRED_H + jb + jA;
  const int rowB = gA*PRED_H + jb + jA + 2;

  float w0xA[10], w0hA[10], w0xB[10], w0hB[10];
  float w1xA[10], w1hA[10], w1xB[10], w1hB[10];
  #pragma unroll
  for (int i = 0; i < 10; ++i){
    int c = lane + (i<<6);
    w0xA[i] = Wih0[(size_t)rowA*PRED_H + c];
    w0hA[i] = Whh0[(size_t)rowA*PRED_H + c];
    w1xA[i] = Wih1[(size_t)rowA*PRED_H + c];
    w1hA[i] = Whh1[(size_t)rowA*PRED_H + c];
    w0xB[i] = Wih0[(size_t)rowB*PRED_H + c];
    w0hB[i] = Whh0[(size_t)rowB*PRED_H + c];
    w1xB[i] = Wih1[(size_t)rowB*PRED_H + c];
    w1hB[i] = Whh1[(size_t)rowB*PRED_H + c];
  }
  const float bA0 = b0[rowA], bA1 = b1[rowA];
  const float bB0 = b0[rowB], bB1 = b1[rowB];

  // ---- Joint1: 4 rows; 2 groups x 2 passes. grp=wave>>2, vt=(wave&3)*64+lane
  const int grp = wave >> 2;
  const int vt  = ((wave & 3)<<6) | lane; // 0..255
  const int rP0 = jb + grp;               // pass-0 row
  const int rP1 = jb + 2 + grp;           // pass-1 row
  float wjf0[4], wjh0[3], wjf1[4], wjh1[3];
  #pragma unroll
  for (int i = 0; i < 4; ++i){
    wjf0[i] = Wj1[(size_t)rP0*(ENC_DIM+PRED_H) + vt + (i<<8)];
    wjf1[i] = Wj1[(size_t)rP1*(ENC_DIM+PRED_H) + vt + (i<<8)];
  }
  #pragma unroll
  for (int i = 0; i < 3; ++i){
    int c = vt + (i<<8);
    wjh0[i] = (c < PRED_H) ? Wj1[(size_t)rP0*(ENC_DIM+PRED_H) + ENC_DIM + c] : 0.f;
    wjh1[i] = (c < PRED_H) ? Wj1[(size_t)rP1*(ENC_DIM+PRED_H) + ENC_DIM + c] : 0.f;
  }
  float ca0 = 0.f, ca1 = 0.f;             // cached f-part partials

  // ---- Joint2: 25/26 rows per WG; wave does rows r2b + p*8 + wave, p<4
  const int nrows = (wg < 96) ? 26 : 25;
  const int r2b = wg*25 + (wg < 96 ? wg : 96);
  float wj2[4][10], bj2r[4];
  #pragma unroll
  for (int p = 0; p < 4; ++p){
    bool act = (p*8 + wave) < nrows;
    int r = act ? (r2b + p*8 + wave) : 0;
    #pragma unroll
    for (int i = 0; i < 10; ++i)
      wj2[p][i] = act ? Wj2[(size_t)r*JOINT_H + lane + (i<<6)] : 0.f;
    bj2r[p] = act ? bj2[r] : 0.f;
  }

  for (int i = tid; i < PRED_H; i += NTHR){ h0buf[0][i] = 0.f; h1buf[0][i] = 0.f; }
  if (tid < 4){ c0c[tid] = 0.f; c1c[tid] = 0.f; bj1sh[tid] = bj1[jb+tid]; }
  __syncthreads();

  int cur = 0, t = 0, sa = 0, last = -1, cnt = 0, tStaged = -1;
  bool done = false, reuse = false;

  for (int s = 0; s < NSTEPS; ++s){
    if (done){
      if (wg < 8) out[(size_t)s*VOCAB + wg*NTHR + tid] = 0.f;
      continue;
    }
    const unsigned tag = (unsigned)(s + 1);

    if (!reuse){
      // ===== A: LSTM layer 0 (inputs all LDS-local) =====
      for (int i = tid; i < PRED_H; i += NTHR)
        xa[i] = (last >= 0) ? emb[(size_t)last*PRED_H + i] : 0.f;
      __syncthreads();
      {
        float acc = 0.f;
        #pragma unroll
        for (int i = 0; i < 10; ++i) acc = fmaf(w0xA[i], xa[lane+(i<<6)], acc);
        #pragma unroll
        for (int i = 0; i < 10; ++i) acc = fmaf(w0hA[i], h0buf[cur][lane+(i<<6)], acc);
        acc = wave_red(acc);
        if (lane == 0) zsh[gA][jA] = acc + bA0;
        float a2 = 0.f;
        #pragma unroll
        for (int i = 0; i < 10; ++i) a2 = fmaf(w0xB[i], xa[lane+(i<<6)], a2);
        #pragma unroll
        for (int i = 0; i < 10; ++i) a2 = fmaf(w0hB[i], h0buf[cur][lane+(i<<6)], a2);
        a2 = wave_red(a2);
        if (lane == 0) zsh[gA][jA+2] = a2 + bB0;
      }
      __syncthreads();
      if (tid < 4){
        float ig = sigf(zsh[0][tid]), fg = sigf(zsh[1][tid]);
        float gg = tanhf(zsh[2][tid]), og = sigf(zsh[3][tid]);
        float c2 = fg*c0c[tid] + ig*gg;
        c0p[tid] = c2;
        tstore(&bufsT[jb+tid], og*tanhf(c2), tag);
      }
      __syncthreads();

      // ===== B: LSTM layer 1 =====
      if (tid < 320) pollchunk(bufsT, h0buf[cur^1], tag, tid);   // h0n
      __syncthreads();
      {
        float acc = 0.f;
        #pragma unroll
        for (int i = 0; i < 10; ++i) acc = fmaf(w1xA[i], h0buf[cur^1][lane+(i<<6)], acc);
        #pragma unroll
        for (int i = 0; i < 10; ++i) acc = fmaf(w1hA[i], h1buf[cur][lane+(i<<6)], acc);
        acc = wave_red(acc);
        if (lane == 0) zsh[gA][jA] = acc + bA1;
        float a2 = 0.f;
        #pragma unroll
        for (int i = 0; i < 10; ++i) a2 = fmaf(w1xB[i], h0buf[cur^1][lane+(i<<6)], a2);
        #pragma unroll
        for (int i = 0; i < 10; ++i) a2 = fmaf(w1hB[i], h1buf[cur][lane+(i<<6)], a2);
        a2 = wave_red(a2);
        if (lane == 0) zsh[gA][jA+2] = a2 + bB1;
      }
      __syncthreads();
      if (tid < 4){
        float ig = sigf(zsh[0][tid]), fg = sigf(zsh[1][tid]);
        float gg = tanhf(zsh[2][tid]), og = sigf(zsh[3][tid]);
        float c2 = fg*c1c[tid] + ig*gg;
        c1p[tid] = c2;
        tstore(&bufsT[PRED_H+jb+tid], og*tanhf(c2), tag);
      }
    }

    // ===== C: joint hidden (4 rows, 2 passes, single sync) =====
    {
      int tcap = (t < TMAX-1) ? t : (TMAX-1);
      bool fNew = (tcap != tStaged);
      if (fNew)
        for (int i = tid; i < ENC_DIM; i += NTHR) xsh[i] = enc[(size_t)tcap*ENC_DIM + i];
      if (!reuse){
        if (tid < 320) pollchunk(bufsT + PRED_H, h1buf[cur^1], tag, tid);  // h1n
      }
      __syncthreads();
      if (fNew){
        float a = 0.f, b = 0.f;
        #pragma unroll
        for (int i = 0; i < 4; ++i){
          a = fmaf(wjf0[i], xsh[vt+(i<<8)], a);
          b = fmaf(wjf1[i], xsh[vt+(i<<8)], b);
        }
        ca0 = a; ca1 = b;
        tStaged = tcap;
      }
      {
        float acc = ca0;
        #pragma unroll
        for (int i = 0; i < 3; ++i){
          int c = vt + (i<<8);
          acc = fmaf(wjh0[i], h1buf[cur^1][(c < PRED_H) ? c : 0], acc);
        }
        acc = wave_red(acc);
        if (lane == 0) zjsA[wave] = acc;
        float acc2 = ca1;
        #pragma unroll
        for (int i = 0; i < 3; ++i){
          int c = vt + (i<<8);
          acc2 = fmaf(wjh1[i], h1buf[cur^1][(c < PRED_H) ? c : 0], acc2);
        }
        acc2 = wave_red(acc2);
        if (lane == 0) zjsB[wave] = acc2;
      }
      __syncthreads();
      if (tid == 0){
        float v0 = zjsA[0]+zjsA[1]+zjsA[2]+zjsA[3] + bj1sh[0];
        tstore(&hidT[jb],   v0 > 0.f ? v0 : 0.f, tag);
        float v1 = zjsA[4]+zjsA[5]+zjsA[6]+zjsA[7] + bj1sh[1];
        tstore(&hidT[jb+1], v1 > 0.f ? v1 : 0.f, tag);
        float v2 = zjsB[0]+zjsB[1]+zjsB[2]+zjsB[3] + bj1sh[2];
        tstore(&hidT[jb+2], v2 > 0.f ? v2 : 0.f, tag);
        float v3 = zjsB[4]+zjsB[5]+zjsB[6]+zjsB[7] + bj1sh[3];
        tstore(&hidT[jb+3], v3 > 0.f ? v3 : 0.f, tag);
      }
    }

    // ===== D: logits + argmax =====
    int k;
    {
      if (tid < 320) pollchunk(hidT, hidsh, tag, tid);      // hid
      __syncthreads();
      u64 best = 0;
      #pragma unroll
      for (int p = 0; p < 4; ++p){
        if (p*8 + wave < nrows){
          int r = r2b + p*8 + wave;
          float acc = 0.f;
          #pragma unroll
          for (int i = 0; i < 10; ++i) acc = fmaf(wj2[p][i], hidsh[lane+(i<<6)], acc);
          acc = wave_red(acc);
          if (lane == 0){
            float lg = acc + bj2r[p];
            out[(size_t)s*VOCAB + r] = lg;
            u64 e = mkentry(lg, r, tag);
            if (e > best) best = e;
          }
        }
      }
      if (lane == 0) psh[wave] = best;
      __syncthreads();
      if (tid == 0){
        u64 m = psh[0];
        #pragma unroll
        for (int w = 1; w < 8; ++w) if (psh[w] > m) m = psh[w];
        __hip_atomic_store(&parts[wg], m, RLX, AGT);
      }
      // all-WG gather of 160 partials
      u64 myp = 0;
      if (tid < 160){
        for(;;){
          u64 e = __hip_atomic_load(&parts[tid], RLX, AGT);
          if ((unsigned)((e>>12) & 0xFFFu) == (tag & 0xFFFu)){ myp = e; break; }
          __builtin_amdgcn_s_sleep(4);
        }
      }
      if (wave < 3){
        #pragma unroll
        for (int off = 32; off; off >>= 1){
          u64 o = __shfl_xor(myp, off, 64);
          if (o > myp) myp = o;
        }
        if (lane == 0) pmx[wave] = myp;
      }
      __syncthreads();
      u64 m = pmx[0];
      if (pmx[1] > m) m = pmx[1];
      if (pmx[2] > m) m = pmx[2];
      k = 4095 - (int)(m & 0xFFFull);
    }

    // ===== E: decision (replicated in every WG) =====
    bool stop = (k == 0) || (sa >= MAX_SYM);
    if (!stop){
      if (wg == 0 && tid == 0) out[(size_t)NSTEPS*VOCAB + cnt] = (float)k;
      if (tid < 4){ c0c[tid] = c0p[tid]; c1c[tid] = c1p[tid]; }
      cnt++; sa++; last = k; cur ^= 1; reuse = false;
    } else {
      sa = 0; t++; reuse = true;
      if (t >= timesteps) done = true;
    }
    __syncthreads();
  }

  // labels tail (-1) and cnt
  size_t lab = (size_t)NSTEPS*VOCAB;
  int gidx = wg*NTHR + tid;
  for (int i = cnt + gidx; i < NSTEPS; i += NWG*NTHR) out[lab + i] = -1.f;
  if (wg == 0 && tid == 0) out[lab + NSTEPS] = (float)cnt;
}

extern "C" void kernel_launch(void* const* d_in, const int* in_sizes, int n_in,
                              void* d_out, int out_size, void* d_ws, size_t ws_size,
                              hipStream_t stream) {
  const float* enc  = (const float*)d_in[0];
  const int*   olen = (const int*)  d_in[1];
  const float* emb  = (const float*)d_in[2];
  const float* Wih0 = (const float*)d_in[3];
  const float* Whh0 = (const float*)d_in[4];
  const float* b0   = (const float*)d_in[5];
  const float* Wih1 = (const float*)d_in[6];
  const float* Whh1 = (const float*)d_in[7];
  const float* b1   = (const float*)d_in[8];
  const float* Wj1  = (const float*)d_in[9];
  const float* bj1  = (const float*)d_in[10];
  const float* Wj2  = (const float*)d_in[11];
  const float* bj2  = (const float*)d_in[12];
  float* out = (float*)d_out;

  u64* parts = (u64*)d_ws;
  u64* bufsT = (u64*)((char*)d_ws + 4096);
  u64* hidT  = (u64*)((char*)d_ws + 14336);

  init_ws<<<1, 256, 0, stream>>>((unsigned*)d_ws);

  void* args[] = {&enc,&olen,&emb,&Wih0,&Whh0,&b0,&Wih1,&Whh1,&b1,
                  &Wj1,&bj1,&Wj2,&bj2,&out,&parts,&bufsT,&hidT};
  hipLaunchCooperativeKernel((const void*)rnnt_decode, dim3(NWG), dim3(NTHR),
                             args, 0, stream);
}

// Round 11
// 47384.216 us; speedup vs baseline: 1.7933x; 1.0621x over previous
//
#include <hip/hip_runtime.h>
#include <cmath>

#define VOCAB   4096
#define ENC_DIM 1024
#define PRED_H  640
#define JOINT_H 640
#define TMAX    128
#define MAX_SYM 30
#define NSTEPS  (TMAX*(MAX_SYM+1))   // 3968
#define NWG     160
#define NTHR    512
#define RLX __ATOMIC_RELAXED
#define AGT __HIP_MEMORY_SCOPE_AGENT

typedef unsigned long long u64;
typedef __attribute__((ext_vector_type(4))) float f32x4;

// ws layout (bytes), everything at 64B line granularity:
//   0      flagA[160 lines]   (u32 tag at line start)
//   10240  flagB[160 lines]
//   20480  flagH[160 lines]
//   30720  dataA[160 lines]   (16B f32x4 chunk at line start: h0n[4w..4w+4))
//   40960  dataB[160 lines]   (h1n)
//   51200  dataH[160 lines]   (hid)
//   61440  parts[160 lines]   (tagged u64 argmax entry at line start)
//   total 71680

__device__ __forceinline__ float wave_red(float v){
  v += __shfl_xor(v, 32, 64);
  v += __shfl_xor(v, 16, 64);
  v += __shfl_xor(v,  8, 64);
  v += __shfl_xor(v,  4, 64);
  v += __shfl_xor(v,  2, 64);
  v += __shfl_xor(v,  1, 64);
  return v;
}

__device__ __forceinline__ float sigf(float x){ return 1.0f/(1.0f+expf(-x)); }

// producer: one 16B data store -> vmcnt(0) -> one flag store (release)
__device__ __forceinline__ void hop_send(float* data, unsigned* flag, int w,
                                         f32x4 v, unsigned tag){
  asm volatile("global_store_dwordx4 %0, %1, off sc0 sc1"
               :: "v"(data + (w<<4)), "v"(v) : "memory");
  asm volatile("s_waitcnt vmcnt(0)" ::: "memory");
  __hip_atomic_store(flag + (w<<4), tag, RLX, AGT);
}

// consumer thread i: poll producer i's flag (own line), then one-shot 16B read
__device__ __forceinline__ void hop_recv(const unsigned* flag, const float* data,
                                         float* dstLDS, unsigned tag, int i){
  const unsigned* fp = flag + (i<<4);
  for(;;){
    unsigned f;
    asm volatile("global_load_dword %0, %1, off sc0 sc1\n\ts_waitcnt vmcnt(0)"
                 : "=v"(f) : "v"(fp) : "memory");
    if (f >= tag) break;                  // monotonic: stale-old impossible by causality
    __builtin_amdgcn_s_sleep(2);
  }
  f32x4 v;
  asm volatile("global_load_dwordx4 %0, %1, off sc0 sc1\n\ts_waitcnt vmcnt(0)"
               : "=v"(v) : "v"(data + (i<<4)) : "memory");
  __builtin_amdgcn_sched_barrier(0);
  *(f32x4*)&dstLDS[i<<2] = v;
}

// argmax entry: key(32b order-preserving) << 24 | (tag&0xFFF)<<12 | (4095-r)
__device__ __forceinline__ u64 mkentry(float lg, int r, unsigned ep){
  unsigned u = __float_as_uint(lg);
  u = (u & 0x80000000u) ? ~u : (u | 0x80000000u);
  return ((u64)u<<24) | ((u64)(ep&0xFFFu)<<12) | (u64)(4095 - r);
}

__global__ void init_ws(unsigned* ws){
  for (int i = threadIdx.x; i < 18432; i += 256) ws[i] = 0u;   // 73728 B
}

__global__ __launch_bounds__(NTHR, 2)
void rnnt_decode(const float* __restrict__ enc,
                 const int*   __restrict__ outlen_p,
                 const float* __restrict__ emb,
                 const float* __restrict__ Wih0, const float* __restrict__ Whh0, const float* __restrict__ b0,
                 const float* __restrict__ Wih1, const float* __restrict__ Whh1, const float* __restrict__ b1,
                 const float* __restrict__ Wj1,  const float* __restrict__ bj1,
                 const float* __restrict__ Wj2,  const float* __restrict__ bj2,
                 float* __restrict__ out,
                 char* __restrict__ ws)
{
  const int wg = blockIdx.x, tid = threadIdx.x;
  const int wave = tid >> 6, lane = tid & 63;
  const int timesteps = outlen_p[0];

  unsigned* flagA = (unsigned*)(ws);
  unsigned* flagB = (unsigned*)(ws + 10240);
  unsigned* flagH = (unsigned*)(ws + 20480);
  float*    dataA = (float*)   (ws + 30720);
  float*    dataB = (float*)   (ws + 40960);
  float*    dataH = (float*)   (ws + 51200);
  u64*      parts = (u64*)     (ws + 61440);

  __shared__ float xa[PRED_H];
  __shared__ float xsh[ENC_DIM];
  __shared__ float h0buf[2][PRED_H];
  __shared__ float h1buf[2][PRED_H];
  __shared__ float hidsh[JOINT_H];
  __shared__ float zsh[4][4];
  __shared__ float zjsA[8], zjsB[8];
  __shared__ float c0c[4], c1c[4], c0p[4], c1p[4];
  __shared__ float bj1sh[4];
  __shared__ u64 psh[8];
  __shared__ u64 pmx[3];

  const int jb = wg*4;                    // uniform: 4 j per WG (640/160)

  // ---- LSTM rows: 16 per WG; wave -> gate gA=wave&3, j's jA=wave>>2 and jA+2
  const int gA = wave & 3;
  const int jA = wave >> 2;               // 0..1
  const int rowA = gA*PRED_H + jb + jA;
  const int rowB = gA*PRED_H + jb + jA + 2;

  float w0xA[10], w0hA[10], w0xB[10], w0hB[10];
  float w1xA[10], w1hA[10], w1xB[10], w1hB[10];
  #pragma unroll
  for (int i = 0; i < 10; ++i){
    int c = lane + (i<<6);
    w0xA[i] = Wih0[(size_t)rowA*PRED_H + c];
    w0hA[i] = Whh0[(size_t)rowA*PRED_H + c];
    w1xA[i] = Wih1[(size_t)rowA*PRED_H + c];
    w1hA[i] = Whh1[(size_t)rowA*PRED_H + c];
    w0xB[i] = Wih0[(size_t)rowB*PRED_H + c];
    w0hB[i] = Whh0[(size_t)rowB*PRED_H + c];
    w1xB[i] = Wih1[(size_t)rowB*PRED_H + c];
    w1hB[i] = Whh1[(size_t)rowB*PRED_H + c];
  }
  const float bA0 = b0[rowA], bA1 = b1[rowA];
  const float bB0 = b0[rowB], bB1 = b1[rowB];

  // ---- Joint1: 4 rows; 2 groups x 2 passes (identical to R10)
  const int grp = wave >> 2;
  const int vt  = ((wave & 3)<<6) | lane; // 0..255
  const int rP0 = jb + grp;
  const int rP1 = jb + 2 + grp;
  float wjf0[4], wjh0[3], wjf1[4], wjh1[3];
  #pragma unroll
  for (int i = 0; i < 4; ++i){
    wjf0[i] = Wj1[(size_t)rP0*(ENC_DIM+PRED_H) + vt + (i<<8)];
    wjf1[i] = Wj1[(size_t)rP1*(ENC_DIM+PRED_H) + vt + (i<<8)];
  }
  #pragma unroll
  for (int i = 0; i < 3; ++i){
    int c = vt + (i<<8);
    wjh0[i] = (c < PRED_H) ? Wj1[(size_t)rP0*(ENC_DIM+PRED_H) + ENC_DIM + c] : 0.f;
    wjh1[i] = (c < PRED_H) ? Wj1[(size_t)rP1*(ENC_DIM+PRED_H) + ENC_DIM + c] : 0.f;
  }
  float ca0 = 0.f, ca1 = 0.f;

  // ---- Joint2: 25/26 rows per WG (identical to R10)
  const int nrows = (wg < 96) ? 26 : 25;
  const int r2b = wg*25 + (wg < 96 ? wg : 96);
  float wj2[4][10], bj2r[4];
  #pragma unroll
  for (int p = 0; p < 4; ++p){
    bool act = (p*8 + wave) < nrows;
    int r = act ? (r2b + p*8 + wave) : 0;
    #pragma unroll
    for (int i = 0; i < 10; ++i)
      wj2[p][i] = act ? Wj2[(size_t)r*JOINT_H + lane + (i<<6)] : 0.f;
    bj2r[p] = act ? bj2[r] : 0.f;
  }

  for (int i = tid; i < PRED_H; i += NTHR){ h0buf[0][i] = 0.f; h1buf[0][i] = 0.f; }
  if (tid < 4){ c0c[tid] = 0.f; c1c[tid] = 0.f; bj1sh[tid] = bj1[jb+tid]; }
  __syncthreads();

  int cur = 0, t = 0, sa = 0, last = -1, cnt = 0, tStaged = -1;
  bool done = false, reuse = false;

  for (int s = 0; s < NSTEPS; ++s){
    if (done){
      if (wg < 8) out[(size_t)s*VOCAB + wg*NTHR + tid] = 0.f;
      continue;
    }
    const unsigned tag = (unsigned)(s + 1);

    if (!reuse){
      // ===== A: LSTM layer 0 (inputs all LDS-local) =====
      for (int i = tid; i < PRED_H; i += NTHR)
        xa[i] = (last >= 0) ? emb[(size_t)last*PRED_H + i] : 0.f;
      __syncthreads();
      {
        float acc = 0.f;
        #pragma unroll
        for (int i = 0; i < 10; ++i) acc = fmaf(w0xA[i], xa[lane+(i<<6)], acc);
        #pragma unroll
        for (int i = 0; i < 10; ++i) acc = fmaf(w0hA[i], h0buf[cur][lane+(i<<6)], acc);
        acc = wave_red(acc);
        if (lane == 0) zsh[gA][jA] = acc + bA0;
        float a2 = 0.f;
        #pragma unroll
        for (int i = 0; i < 10; ++i) a2 = fmaf(w0xB[i], xa[lane+(i<<6)], a2);
        #pragma unroll
        for (int i = 0; i < 10; ++i) a2 = fmaf(w0hB[i], h0buf[cur][lane+(i<<6)], a2);
        a2 = wave_red(a2);
        if (lane == 0) zsh[gA][jA+2] = a2 + bB0;
      }
      __syncthreads();
      if (wave == 0){
        float hv = 0.f;
        if (lane < 4){
          float ig = sigf(zsh[0][lane]), fg = sigf(zsh[1][lane]);
          float gg = tanhf(zsh[2][lane]), og = sigf(zsh[3][lane]);
          float c2 = fg*c0c[lane] + ig*gg;
          c0p[lane] = c2;
          hv = og*tanhf(c2);
        }
        f32x4 v;
        v.x = __shfl(hv, 0, 64); v.y = __shfl(hv, 1, 64);
        v.z = __shfl(hv, 2, 64); v.w = __shfl(hv, 3, 64);
        if (lane == 0) hop_send(dataA, flagA, wg, v, tag);
      }

      // ===== B: LSTM layer 1 =====
      if (tid < 160) hop_recv(flagA, dataA, h0buf[cur^1], tag, tid);
      __syncthreads();
      {
        float acc = 0.f;
        #pragma unroll
        for (int i = 0; i < 10; ++i) acc = fmaf(w1xA[i], h0buf[cur^1][lane+(i<<6)], acc);
        #pragma unroll
        for (int i = 0; i < 10; ++i) acc = fmaf(w1hA[i], h1buf[cur][lane+(i<<6)], acc);
        acc = wave_red(acc);
        if (lane == 0) zsh[gA][jA] = acc + bA1;
        float a2 = 0.f;
        #pragma unroll
        for (int i = 0; i < 10; ++i) a2 = fmaf(w1xB[i], h0buf[cur^1][lane+(i<<6)], a2);
        #pragma unroll
        for (int i = 0; i < 10; ++i) a2 = fmaf(w1hB[i], h1buf[cur][lane+(i<<6)], a2);
        a2 = wave_red(a2);
        if (lane == 0) zsh[gA][jA+2] = a2 + bB1;
      }
      __syncthreads();
      if (wave == 0){
        float hv = 0.f;
        if (lane < 4){
          float ig = sigf(zsh[0][lane]), fg = sigf(zsh[1][lane]);
          float gg = tanhf(zsh[2][lane]), og = sigf(zsh[3][lane]);
          float c2 = fg*c1c[lane] + ig*gg;
          c1p[lane] = c2;
          hv = og*tanhf(c2);
        }
        f32x4 v;
        v.x = __shfl(hv, 0, 64); v.y = __shfl(hv, 1, 64);
        v.z = __shfl(hv, 2, 64); v.w = __shfl(hv, 3, 64);
        if (lane == 0) hop_send(dataB, flagB, wg, v, tag);
      }
    }

    // ===== C: joint hidden (4 rows, 2 passes) =====
    {
      int tcap = (t < TMAX-1) ? t : (TMAX-1);
      bool fNew = (tcap != tStaged);
      if (fNew)
        for (int i = tid; i < ENC_DIM; i += NTHR) xsh[i] = enc[(size_t)tcap*ENC_DIM + i];
      if (!reuse){
        if (tid < 160) hop_recv(flagB, dataB, h1buf[cur^1], tag, tid);
      }
      __syncthreads();
      if (fNew){
        float a = 0.f, b = 0.f;
        #pragma unroll
        for (int i = 0; i < 4; ++i){
          a = fmaf(wjf0[i], xsh[vt+(i<<8)], a);
          b = fmaf(wjf1[i], xsh[vt+(i<<8)], b);
        }
        ca0 = a; ca1 = b;
        tStaged = tcap;
      }
      {
        float acc = ca0;
        #pragma unroll
        for (int i = 0; i < 3; ++i){
          int c = vt + (i<<8);
          acc = fmaf(wjh0[i], h1buf[cur^1][(c < PRED_H) ? c : 0], acc);
        }
        acc = wave_red(acc);
        if (lane == 0) zjsA[wave] = acc;
        float acc2 = ca1;
        #pragma unroll
        for (int i = 0; i < 3; ++i){
          int c = vt + (i<<8);
          acc2 = fmaf(wjh1[i], h1buf[cur^1][(c < PRED_H) ? c : 0], acc2);
        }
        acc2 = wave_red(acc2);
        if (lane == 0) zjsB[wave] = acc2;
      }
      __syncthreads();
      if (wave == 0){
        float hv = 0.f;
        if (lane < 4){
          float v;
          if (lane == 0)      v = zjsA[0]+zjsA[1]+zjsA[2]+zjsA[3] + bj1sh[0];
          else if (lane == 1) v = zjsA[4]+zjsA[5]+zjsA[6]+zjsA[7] + bj1sh[1];
          else if (lane == 2) v = zjsB[0]+zjsB[1]+zjsB[2]+zjsB[3] + bj1sh[2];
          else                v = zjsB[4]+zjsB[5]+zjsB[6]+zjsB[7] + bj1sh[3];
          hv = v > 0.f ? v : 0.f;
        }
        f32x4 v;
        v.x = __shfl(hv, 0, 64); v.y = __shfl(hv, 1, 64);
        v.z = __shfl(hv, 2, 64); v.w = __shfl(hv, 3, 64);
        if (lane == 0) hop_send(dataH, flagH, wg, v, tag);
      }
    }

    // ===== D: logits + argmax =====
    int k;
    {
      if (tid < 160) hop_recv(flagH, dataH, hidsh, tag, tid);
      __syncthreads();
      u64 best = 0;
      #pragma unroll
      for (int p = 0; p < 4; ++p){
        if (p*8 + wave < nrows){
          int r = r2b + p*8 + wave;
          float acc = 0.f;
          #pragma unroll
          for (int i = 0; i < 10; ++i) acc = fmaf(wj2[p][i], hidsh[lane+(i<<6)], acc);
          acc = wave_red(acc);
          if (lane == 0){
            float lg = acc + bj2r[p];
            out[(size_t)s*VOCAB + r] = lg;
            u64 e = mkentry(lg, r, tag);
            if (e > best) best = e;
          }
        }
      }
      if (lane == 0) psh[wave] = best;
      __syncthreads();
      if (tid == 0){
        u64 m = psh[0];
        #pragma unroll
        for (int w = 1; w < 8; ++w) if (psh[w] > m) m = psh[w];
        __hip_atomic_store(&parts[(size_t)wg<<3], m, RLX, AGT);
      }
      // all-WG gather of 160 tagged partials (64B stride)
      u64 myp = 0;
      if (tid < 160){
        for(;;){
          u64 e = __hip_atomic_load(&parts[(size_t)tid<<3], RLX, AGT);
          if ((unsigned)((e>>12) & 0xFFFu) == (tag & 0xFFFu)){ myp = e; break; }
          __builtin_amdgcn_s_sleep(2);
        }
      }
      if (wave < 3){
        #pragma unroll
        for (int off = 32; off; off >>= 1){
          u64 o = __shfl_xor(myp, off, 64);
          if (o > myp) myp = o;
        }
        if (lane == 0) pmx[wave] = myp;
      }
      __syncthreads();
      u64 m = pmx[0];
      if (pmx[1] > m) m = pmx[1];
      if (pmx[2] > m) m = pmx[2];
      k = 4095 - (int)(m & 0xFFFull);
    }

    // ===== E: decision (replicated in every WG) =====
    bool stop = (k == 0) || (sa >= MAX_SYM);
    if (!stop){
      if (wg == 0 && tid == 0) out[(size_t)NSTEPS*VOCAB + cnt] = (float)k;
      if (tid < 4){ c0c[tid] = c0p[tid]; c1c[tid] = c1p[tid]; }
      cnt++; sa++; last = k; cur ^= 1; reuse = false;
    } else {
      sa = 0; t++; reuse = true;
      if (t >= timesteps) done = true;
    }
    __syncthreads();
  }

  // labels tail (-1) and cnt
  size_t lab = (size_t)NSTEPS*VOCAB;
  int gidx = wg*NTHR + tid;
  for (int i = cnt + gidx; i < NSTEPS; i += NWG*NTHR) out[lab + i] = -1.f;
  if (wg == 0 && tid == 0) out[lab + NSTEPS] = (float)cnt;
}

extern "C" void kernel_launch(void* const* d_in, const int* in_sizes, int n_in,
                              void* d_out, int out_size, void* d_ws, size_t ws_size,
                              hipStream_t stream) {
  const float* enc  = (const float*)d_in[0];
  const int*   olen = (const int*)  d_in[1];
  const float* emb  = (const float*)d_in[2];
  const float* Wih0 = (const float*)d_in[3];
  const float* Whh0 = (const float*)d_in[4];
  const float* b0   = (const float*)d_in[5];
  const float* Wih1 = (const float*)d_in[6];
  const float* Whh1 = (const float*)d_in[7];
  const float* b1   = (const float*)d_in[8];
  const float* Wj1  = (const float*)d_in[9];
  const float* bj1  = (const float*)d_in[10];
  const float* Wj2  = (const float*)d_in[11];
  const float* bj2  = (const float*)d_in[12];
  float* out = (float*)d_out;
  char* ws = (char*)d_ws;

  init_ws<<<1, 256, 0, stream>>>((unsigned*)d_ws);

  void* args[] = {&enc,&olen,&emb,&Wih0,&Whh0,&b0,&Wih1,&Whh1,&b1,
                  &Wj1,&bj1,&Wj2,&bj2,&out,&ws};
  hipLaunchCooperativeKernel((const void*)rnnt_decode, dim3(NWG), dim3(NTHR),
                             args, 0, stream);
}